// Round 1
// baseline (400.388 us; speedup 1.0000x reference)
//
#include <hip/hip_runtime.h>

// ForceAggregation: f[m] = H[m] @ x[m] + DAMP_FACTOR * x[m]
// M=8192 molecules, D=96 (32 atoms * 3). Batched 96x96 matvec, HBM-bound:
// hess is 302 MB read exactly once -> roofline ~49 us at 6.3 TB/s.

#define D_DIM   96
#define QROW    24              // float4 per hessian row (96/4)
#define QMOL    (D_DIM * QROW)  // 2304 float4 per molecule
#define BLOCK   256
#define ITERS   (QMOL / BLOCK)  // 9 float4 per thread
#define PSTRIDE 25              // partial-sum row stride: 25*r mod 32 distinct
                                // per lane -> conflict-free pass-2 LDS reads

__global__ __launch_bounds__(BLOCK)
void force_agg_kernel(const float* __restrict__ hess,
                      const float* __restrict__ ns,
                      float* __restrict__ out)
{
    __shared__ __align__(16) float xs[D_DIM];
    __shared__ float partial[D_DIM * PSTRIDE];  // 9.6 KB

    const int m = blockIdx.x;
    const int t = threadIdx.x;
    const float4* H4 = reinterpret_cast<const float4*>(hess) + (size_t)m * QMOL;

    // stage x for this molecule (96 consecutive floats, coalesced)
    if (t < D_DIM) xs[t] = ns[(size_t)m * D_DIM + t];
    __syncthreads();

    const float4* X4 = reinterpret_cast<const float4*>(xs);

    // pass 1: each thread dots 9 coalesced float4 of H against x4, writes
    // scalar partials to LDS. Consecutive lanes -> consecutive 16B of H.
#pragma unroll
    for (int i = 0; i < ITERS; ++i) {
        const int q   = t + i * BLOCK;
        const int row = q / QROW;           // magic-mul div by 24
        const int k   = q - row * QROW;
        const float4 h  = H4[q];
        const float4 xv = X4[k];
        partial[row * PSTRIDE + k] = h.x * xv.x + h.y * xv.y
                                   + h.z * xv.z + h.w * xv.w;
    }
    __syncthreads();

    // pass 2: threads 0..95 reduce 24 partials per output row, add damping.
    if (t < D_DIM) {
        float s = 0.0f;
#pragma unroll
        for (int k = 0; k < QROW; ++k) s += partial[t * PSTRIDE + k];
        const float DAMP =
            (float)(0.1 * 627.5094740631 / (0.529177210903 * 0.529177210903));
        out[(size_t)m * D_DIM + t] = s + DAMP * xs[t];
    }
}

extern "C" void kernel_launch(void* const* d_in, const int* in_sizes, int n_in,
                              void* d_out, int out_size, void* d_ws, size_t ws_size,
                              hipStream_t stream)
{
    const float* ns   = (const float*)d_in[0];  // [M*32, 3] fp32
    const float* hess = (const float*)d_in[1];  // [M*96, 96] fp32
    // d_in[2] (idx_m) and d_in[3] (n_atoms) are degenerate: uniform molecule
    // size makes the masked gathers pure reshapes -> unused.
    float* out = (float*)d_out;                 // [M*32, 3] fp32

    const int M = in_sizes[0] / D_DIM;          // 786432 / 96 = 8192
    force_agg_kernel<<<M, BLOCK, 0, stream>>>(hess, ns, out);
}